// Round 15
// baseline (308.539 us; speedup 1.0000x reference)
//
#include <hip/hip_runtime.h>
#include <hip/hip_bf16.h>
#include <stdint.h>

#define HW 4096
#define C_ 256
#define B_ 4

static const size_t CHW = (size_t)C_ * HW;  // 1,048,576 elements per batch per tensor

typedef _Float16 f16;
typedef f16 f16x8 __attribute__((ext_vector_type(8)));
typedef float f32x4 __attribute__((ext_vector_type(4)));

#define AS1 __attribute__((address_space(1)))
#define AS3 __attribute__((address_space(3)))
#define GLL(src, dst) __builtin_amdgcn_global_load_lds((const AS1 uint32_t*)(src), (AS3 uint32_t*)(dst), 16, 0, 0)

// ---------- helpers ----------
__device__ __forceinline__ unsigned long long pack_key(float v, int i) {
    unsigned u = __float_as_uint(v);
    u = (u & 0x80000000u) ? ~u : (u | 0x80000000u);
    return ((unsigned long long)u << 32) | (unsigned long long)(0xFFFFFFFFu - (unsigned)i);
}

// ---------- K1a: per-pixel partial squared sums (8 channel-groups) ----------
__global__ __launch_bounds__(256) void sqsum_kernel(const float* __restrict__ frb,
                                                    float* __restrict__ sbuf) {
    int b = blockIdx.x;
    int ij = blockIdx.y * 256 + threadIdx.x;
    int g = blockIdx.z;
    const float* p = frb + (size_t)b * CHW + (size_t)g * 32 * HW + ij;
    float s = 0.f;
#pragma unroll 8
    for (int c = 0; c < 32; ++c) {
        float v = p[(size_t)c * HW];
        s = fmaf(v, v, s);
    }
    sbuf[((size_t)b * 8 + g) * HW + ij] = s;
}

// ---------- K1b: sum partials -> 3x3 box sum -> 1/max(sqrt, eps) ----------
__global__ __launch_bounds__(256) void invn_kernel(const float* __restrict__ sbuf,
                                                   float* __restrict__ invn) {
    int b = blockIdx.x;
    int l = blockIdx.y * 256 + threadIdx.x;
    int lh = l >> 6, lw = l & 63;
    float s = 0.f;
#pragma unroll
    for (int dh = -1; dh <= 1; ++dh) {
        int h = lh + dh;
        if ((unsigned)h >= 64u) continue;
#pragma unroll
        for (int dw = -1; dw <= 1; ++dw) {
            int w = lw + dw;
            if ((unsigned)w >= 64u) continue;
            float t = 0.f;
#pragma unroll
            for (int g = 0; g < 8; ++g)
                t += sbuf[((size_t)b * 8 + g) * HW + h * 64 + w];
            s += t;
        }
    }
    float n = sqrtf(s);
    invn[b * HW + l] = 1.0f / fmaxf(n, 1e-12f);
}

// ---------- conv: fp32 [256][4096] -> f16 hi/lo, m-major [4096][512] ----------
__global__ __launch_bounds__(256) void conv_kernel(const float* __restrict__ fcB,
                                                   const float* __restrict__ frbB,
                                                   f16* __restrict__ AB) {
    int zz = blockIdx.z;
    int b = zz >> 1;
    const float* src = ((zz & 1) ? frbB : fcB) + (size_t)b * CHW;
    f16* dst = AB + (size_t)b * 4194304 + (size_t)(zz & 1) * 2097152;
    __shared__ float T[64][65];
    int m0 = blockIdx.x * 64, k0 = blockIdx.y * 64;
    int t = threadIdx.x;
    int kl = t >> 4, mq = (t & 15) * 4;
#pragma unroll
    for (int it = 0; it < 4; ++it) {
        float4 v = *reinterpret_cast<const float4*>(src + (size_t)(k0 + kl + it * 16) * HW + m0 + mq);
        T[kl + it * 16][mq + 0] = v.x;
        T[kl + it * 16][mq + 1] = v.y;
        T[kl + it * 16][mq + 2] = v.z;
        T[kl + it * 16][mq + 3] = v.w;
    }
    __syncthreads();
    int ml = t >> 2, kc = (t & 3) * 16;
    f16x8 h0, h1, lo0, lo1;
#pragma unroll
    for (int j = 0; j < 8; ++j) {
        float a = T[kc + j][ml];
        f16 h = (f16)a;
        h0[j] = h;
        lo0[j] = (f16)(a - (float)h);
        float a2 = T[kc + 8 + j][ml];
        f16 h2 = (f16)a2;
        h1[j] = h2;
        lo1[j] = (f16)(a2 - (float)h2);
    }
    size_t base = (size_t)(m0 + ml) * 512 + k0 + kc;
    *reinterpret_cast<f16x8*>(dst + base) = h0;
    *reinterpret_cast<f16x8*>(dst + base + 8) = h1;
    *reinterpret_cast<f16x8*>(dst + base + 256) = lo0;
    *reinterpret_cast<f16x8*>(dst + base + 264) = lo1;
}

// ---------- K2 (MFMA, 256^2 8-phase): G = 3-product fp16-split Gram, K=768 ----------
// Tile 256x256, BK=64, 512 thr = 8 waves (2M x 4N), per-wave 128x64.
// LDS (dynamic 128 KB): per operand 2 slots x 2 kk-halves x [256 rows x 32 k] f16.
// kk-half lifetimes end mid-tile -> counted vmcnt(4) at phases 2 & 4 (never 0).
// Per phase: {ds_read 8|4 x b128 | stage 1 half (2 gload_lds)} -> barrier ->
// setprio(1) -> 16 MFMA -> setprio(0) -> [vmcnt] -> barrier.
// Accumulation order (t asc, kk0 then kk1) identical to the 128^2 kernel ->
// G bit-identical -> argmax decisions unchanged.
__global__ __launch_bounds__(512, 2) void gram256_kernel(const f16* __restrict__ ABbase,
                                                         float* __restrict__ Gbase) {
    extern __shared__ char lds[];
    char* ldsA = lds;            // 65536 B
    char* ldsB = lds + 65536;    // 65536 B
    const f16* Af = ABbase;
    const f16* Bf = Af + 2097152;
    float* G = Gbase;

    int tid = threadIdx.x;
    int lane = tid & 63;
    int wave = tid >> 6;
    int wr = wave >> 2, wc = wave & 3;

    // XCD-affinity remap of the 16x16 grid (bijective; dispatch id x-fastest)
    int id = blockIdx.y * 16 + blockIdx.x;
    int xcd = id & 7, local = id >> 3;       // local 0..31
    int bx = (xcd & 1) * 8 + (local & 7);    // 0..15
    int by = (xcd >> 1) * 4 + (local >> 3);  // 0..15
    int m0 = by * 256, l0 = bx * 256;

    f32x4 acc[8][4] = {};

    // staging sources: thread handles rows r0 (i=0) and r0+128 (i=1), chunk s0
    int r0 = tid >> 2, s0 = tid & 3;
    const char* sA0 = (const char*)Af + (size_t)(m0 + r0) * 1024 + ((s0 ^ (r0 & 3)) << 4);
    const char* sB0 = (const char*)Bf + (size_t)(l0 + r0) * 1024 + ((s0 ^ (r0 & 3)) << 4);
    unsigned wbase = (unsigned)(tid & ~63) * 16;  // wave-uniform LDS dest base

#define STAGE_A(su, h, kb)                                                       \
    do {                                                                         \
        GLL(sA0 + (kb) + (h) * 64, ldsA + (su) * 32768 + (h) * 16384 + wbase);   \
        GLL(sA0 + 131072 + (kb) + (h) * 64,                                      \
            ldsA + (su) * 32768 + (h) * 16384 + wbase + 8192);                   \
    } while (0)
#define STAGE_B(su, h, kb)                                                       \
    do {                                                                         \
        GLL(sB0 + (kb) + (h) * 64, ldsB + (su) * 32768 + (h) * 16384 + wbase);   \
        GLL(sB0 + 131072 + (kb) + (h) * 64,                                      \
            ldsB + (su) * 32768 + (h) * 16384 + wbase + 8192);                   \
    } while (0)

    // LDS read bases: swizzle slot = (lane>>4) ^ (row&3); row&3 == lane&3 here
    unsigned rsw = (unsigned)(((lane >> 4) ^ (lane & 3)) << 4);
    unsigned aRow = (unsigned)((wr * 128 + (lane & 15)) * 64) + rsw;
    unsigned bRow = (unsigned)((wc * 64 + (lane & 15)) * 64) + rsw;

    const int akbArr[12] = {0, 128, 256, 384, 512, 640, 768, 896, 0, 128, 256, 384};
    const int bkbArr[12] = {0, 128, 256, 384, 0, 128, 256, 384, 512, 640, 768, 896};

    // prologue: stage tile 0 fully, drain, publish
    STAGE_A(0, 0, akbArr[0]);
    STAGE_B(0, 0, bkbArr[0]);
    STAGE_A(0, 1, akbArr[0]);
    STAGE_B(0, 1, bkbArr[0]);
    asm volatile("s_waitcnt vmcnt(0)" ::: "memory");
    __builtin_amdgcn_s_barrier();

    f16x8 av[4], bv[4];
#pragma unroll
    for (int t = 0; t < 12; ++t) {
        const int slot = t & 1, su = slot ^ 1;
        const bool pf = (t < 11);
        const int akbN = pf ? akbArr[t + 1] : 0;
        const int bkbN = pf ? bkbArr[t + 1] : 0;
        const char* Ab0 = ldsA + slot * 32768;            // kk0 half
        const char* Bb0 = ldsB + slot * 32768;
        const char* Ab1 = Ab0 + 16384;                    // kk1 half
        const char* Bb1 = Bb0 + 16384;

        // ---- phase 1: (kk0, m-lo) ----
#pragma unroll
        for (int ni = 0; ni < 4; ++ni)
            bv[ni] = *reinterpret_cast<const f16x8*>(Bb0 + bRow + ni * 1024);
#pragma unroll
        for (int q = 0; q < 4; ++q)
            av[q] = *reinterpret_cast<const f16x8*>(Ab0 + aRow + q * 1024);
        if (pf) STAGE_A(su, 0, akbN);
        __builtin_amdgcn_s_barrier();
        __builtin_amdgcn_s_setprio(1);
#pragma unroll
        for (int q = 0; q < 4; ++q)
#pragma unroll
            for (int ni = 0; ni < 4; ++ni)
                acc[q][ni] = __builtin_amdgcn_mfma_f32_16x16x32_f16(av[q], bv[ni], acc[q][ni], 0, 0, 0);
        __builtin_amdgcn_s_setprio(0);
        __builtin_amdgcn_s_barrier();

        // ---- phase 2: (kk0, m-hi) ----
#pragma unroll
        for (int q = 0; q < 4; ++q)
            av[q] = *reinterpret_cast<const f16x8*>(Ab0 + aRow + 4096 + q * 1024);
        if (pf) STAGE_B(su, 0, bkbN);
        __builtin_amdgcn_s_barrier();
        __builtin_amdgcn_s_setprio(1);
#pragma unroll
        for (int q = 0; q < 4; ++q)
#pragma unroll
            for (int ni = 0; ni < 4; ++ni)
                acc[4 + q][ni] = __builtin_amdgcn_mfma_f32_16x16x32_f16(av[q], bv[ni], acc[4 + q][ni], 0, 0, 0);
        __builtin_amdgcn_s_setprio(0);
        if (t < 11) asm volatile("s_waitcnt vmcnt(4)" ::: "memory");
        else        asm volatile("s_waitcnt vmcnt(0)" ::: "memory");
        __builtin_amdgcn_s_barrier();

        // ---- phase 3: (kk1, m-lo) ----
#pragma unroll
        for (int ni = 0; ni < 4; ++ni)
            bv[ni] = *reinterpret_cast<const f16x8*>(Bb1 + bRow + ni * 1024);
#pragma unroll
        for (int q = 0; q < 4; ++q)
            av[q] = *reinterpret_cast<const f16x8*>(Ab1 + aRow + q * 1024);
        if (pf) STAGE_A(su, 1, akbN);
        __builtin_amdgcn_s_barrier();
        __builtin_amdgcn_s_setprio(1);
#pragma unroll
        for (int q = 0; q < 4; ++q)
#pragma unroll
            for (int ni = 0; ni < 4; ++ni)
                acc[q][ni] = __builtin_amdgcn_mfma_f32_16x16x32_f16(av[q], bv[ni], acc[q][ni], 0, 0, 0);
        __builtin_amdgcn_s_setprio(0);
        __builtin_amdgcn_s_barrier();

        // ---- phase 4: (kk1, m-hi) ----
#pragma unroll
        for (int q = 0; q < 4; ++q)
            av[q] = *reinterpret_cast<const f16x8*>(Ab1 + aRow + 4096 + q * 1024);
        if (pf) STAGE_B(su, 1, bkbN);
        __builtin_amdgcn_s_barrier();
        __builtin_amdgcn_s_setprio(1);
#pragma unroll
        for (int q = 0; q < 4; ++q)
#pragma unroll
            for (int ni = 0; ni < 4; ++ni)
                acc[4 + q][ni] = __builtin_amdgcn_mfma_f32_16x16x32_f16(av[q], bv[ni], acc[4 + q][ni], 0, 0, 0);
        __builtin_amdgcn_s_setprio(0);
        if (t < 11) asm volatile("s_waitcnt vmcnt(4)" ::: "memory");
        __builtin_amdgcn_s_barrier();
    }
#undef STAGE_A
#undef STAGE_B

    // epilogue: C/D layout col=lane&15, row=(lane>>4)*4+r
#pragma unroll
    for (int mi = 0; mi < 8; ++mi) {
#pragma unroll
        for (int ni = 0; ni < 4; ++ni) {
            int n = l0 + wc * 64 + ni * 16 + (lane & 15);
            int mr = m0 + wr * 128 + mi * 16 + (lane >> 4) * 4;
#pragma unroll
            for (int r = 0; r < 4; ++r)
                G[(size_t)(mr + r) * HW + n] = acc[mi][ni][r];
        }
    }
}

// ---------- K2 fallback: fp32 Gram GEMM (chunked) ----------
#define TBK 32
__global__ __launch_bounds__(256) void gram_kernel(const float* __restrict__ Amat,
                                                   const float* __restrict__ Bmat,
                                                   float* __restrict__ G,
                                                   int l_start, int CWP) {
    __shared__ float As[TBK][128];
    __shared__ float Bs[TBK][128];
    int m0 = blockIdx.y * 128;
    int l0g = l_start + blockIdx.x * 128;
    bool inrange = (l0g >= 0 && l0g < HW);
    int tid = threadIdx.x;
    int tx = tid & 15;
    int ty = tid >> 4;
    float acc[8][8] = {};

    if (inrange) {
        for (int k0 = 0; k0 < C_; k0 += TBK) {
#pragma unroll
            for (int it = 0; it < 4; ++it) {
                int idx = tid + it * 256;
                int r = idx >> 5;
                int c4 = idx & 31;
                float4 av = *reinterpret_cast<const float4*>(Amat + (size_t)(k0 + r) * HW + m0 + c4 * 4);
                *reinterpret_cast<float4*>(&As[r][c4 * 4]) = av;
                float4 bv = *reinterpret_cast<const float4*>(Bmat + (size_t)(k0 + r) * HW + l0g + c4 * 4);
                *reinterpret_cast<float4*>(&Bs[r][c4 * 4]) = bv;
            }
            __syncthreads();
#pragma unroll
            for (int k = 0; k < TBK; ++k) {
                float a[8], bb[8];
                *(float4*)&a[0] = *(float4*)&As[k][ty * 8];
                *(float4*)&a[4] = *(float4*)&As[k][ty * 8 + 4];
                *(float4*)&bb[0] = *(float4*)&Bs[k][tx * 8];
                *(float4*)&bb[4] = *(float4*)&Bs[k][tx * 8 + 4];
#pragma unroll
                for (int i = 0; i < 8; ++i)
#pragma unroll
                    for (int j = 0; j < 8; ++j)
                        acc[i][j] = fmaf(a[i], bb[j], acc[i][j]);
            }
            __syncthreads();
        }
    }
#pragma unroll
    for (int i = 0; i < 8; ++i) {
        int m = m0 + ty * 8 + i;
        float* row = G + (size_t)m * CWP + blockIdx.x * 128 + tx * 8;
        *(float4*)row = *(float4*)&acc[i][0];
        *(float4*)(row + 4) = *(float4*)&acc[i][4];
    }
}

// ---------- K3 (v3): diagonal-separable 9-shift sum + argmax ----------
// EXACT r11-proven config: __launch_bounds__(512,4), grid (64,8), 8-chunk segs.
__global__ __launch_bounds__(512, 4) void argmax3_kernel(const float* __restrict__ Gbase,
                                                         const float* __restrict__ invnB,
                                                         unsigned long long* __restrict__ keysB) {
    const float* G = Gbase + (size_t)blockIdx.z * ((size_t)HW * HW);
    const float* invn = invnB + (size_t)blockIdx.z * HW;
    unsigned long long* keys = keysB + (size_t)blockIdx.z * HW;

    int id = blockIdx.y * gridDim.x + blockIdx.x;  // 0..511
    int xcd = id & 7, pos = id >> 3;               // pos 0..63
    int mh = xcd * 8 + (pos >> 3);
    int c0 = (pos & 7) * 8;

    int lane = threadIdx.x & 63;
    int wave = threadIdx.x >> 6;
    int mwb = wave * 8;

    bool laneUp = lane >= 1, laneDn = lane <= 62;
    bool mhUp = mh >= 1, mhDn = mh <= 62;

    unsigned rowOff[3][10];
    int br0 = max(mh - 1, 0) * 64, br1 = mh * 64, br2 = min(mh + 1, 63) * 64;
#pragma unroll
    for (int j = 0; j < 10; ++j) {
        int mwr = min(max(mwb - 1 + j, 0), 63);
        rowOff[0][j] = (unsigned)((br0 + mwr) * 4096 + lane);
        rowOff[1][j] = (unsigned)((br1 + mwr) * 4096 + lane);
        rowOff[2][j] = (unsigned)((br2 + mwr) * 4096 + lane);
    }

    float A[8], B[8];
#pragma unroll
    for (int i = 0; i < 8; ++i) { A[i] = 0.f; B[i] = 0.f; }
    float maxv[8];
    int maxi[8];
#pragma unroll
    for (int i = 0; i < 8; ++i) { maxv[i] = -INFINITY; maxi[i] = 0; }
    float invPrev = 0.f;

    for (int c = c0 - 1; c <= c0 + 8; ++c) {
        int cc = min(max(c, 0), 63);
        unsigned colOff = (unsigned)(cc * 64);
        float g[3][10];
#pragma unroll
        for (int b = 0; b < 3; ++b)
#pragma unroll
            for (int j = 0; j < 10; ++j)
                g[b][j] = G[(size_t)(rowOff[b][j] + colOff)];
        float invCur = invn[colOff + lane];

        if (c - 1 >= c0) {
            bool vp = mhDn && (c <= 63);
            int lbase = (c - 1) * 64 + lane;
#pragma unroll
            for (int i = 0; i < 8; ++i) {
                float up = __shfl_up(g[2][i], 1);
                float dn = __shfl_down(g[2][i + 2], 1);
                float w = g[2][i + 1];
                w += (laneUp && (mwb + i >= 1)) ? up : 0.f;
                w += (laneDn && (mwb + i <= 62)) ? dn : 0.f;
                float R = A[i] + (vp ? w : 0.f);
                float score = R * invPrev;
                if (score > maxv[i]) { maxv[i] = score; maxi[i] = lbase; }
            }
        }
        bool vm = mhUp && (c >= 0);
#pragma unroll
        for (int i = 0; i < 8; ++i) {
            float up1 = __shfl_up(g[1][i], 1);
            float dn1 = __shfl_down(g[1][i + 2], 1);
            float w1 = g[1][i + 1];
            w1 += (laneUp && (mwb + i >= 1)) ? up1 : 0.f;
            w1 += (laneDn && (mwb + i <= 62)) ? dn1 : 0.f;
            A[i] = B[i] + w1;

            float up0 = __shfl_up(g[0][i], 1);
            float dn0 = __shfl_down(g[0][i + 2], 1);
            float w0 = g[0][i + 1];
            w0 += (laneUp && (mwb + i >= 1)) ? up0 : 0.f;
            w0 += (laneDn && (mwb + i <= 62)) ? dn0 : 0.f;
            B[i] = vm ? w0 : 0.f;
        }
        invPrev = invCur;
    }

#pragma unroll
    for (int i = 0; i < 8; ++i) {
        float v = maxv[i];
        int idx = maxi[i];
#pragma unroll
        for (int off = 32; off >= 1; off >>= 1) {
            float v2 = __shfl_xor(v, off);
            int i2 = __shfl_xor(idx, off);
            if (v2 > v || (v2 == v && i2 < idx)) { v = v2; idx = i2; }
        }
        if (lane == 0) atomicMax(&keys[mh * 64 + mwb + i], pack_key(v, idx));
    }
}

// ---------- K3 fallback (chunked-G path): tap kernel ----------
__global__ __launch_bounds__(512, 8) void argmax_kernel(const float* __restrict__ Gbase,
                                                        const float* __restrict__ invnB,
                                                        unsigned long long* __restrict__ keysB,
                                                        int lh0, int l_start, int CWP) {
    const float* G = Gbase;
    const float* invn = invnB;
    unsigned long long* keys = keysB;
    int mh = blockIdx.x;
    int lh_base = lh0 + blockIdx.y * 4;
    int wave = threadIdx.x >> 6;
    int lane = threadIdx.x & 63;
    int mwbase = wave * 8;

    float maxv[8];
    int maxi[8];
#pragma unroll
    for (int i = 0; i < 8; ++i) { maxv[i] = -INFINITY; maxi[i] = 0; }

    for (int lhs = 0; lhs < 4; ++lhs) {
        int lh = lh_base + lhs;
        int l = lh * 64 + lane;
        float inv = invn[l];
        float R[8];
#pragma unroll
        for (int i = 0; i < 8; ++i) R[i] = 0.f;

#pragma unroll
        for (int dh = -1; dh <= 1; ++dh) {
            if ((unsigned)(mh + dh) >= 64u || (unsigned)(lh + dh) >= 64u) continue;
            const float* Gb = G + (size_t)((mh + dh) * 64) * CWP + ((lh + dh) * 64 - l_start) + lane;
            float v[10];
#pragma unroll
            for (int j = 0; j < 10; ++j) {
                int mw2 = mwbase - 1 + j;
                int mwc = min(max(mw2, 0), 63);
                float tv = Gb[(size_t)mwc * CWP];
                v[j] = ((unsigned)mw2 < 64u) ? tv : 0.f;
            }
#pragma unroll
            for (int mi = 0; mi < 8; ++mi) {
                float a = __shfl_up(v[mi], 1);
                float c = __shfl_down(v[mi + 2], 1);
                float s = v[mi + 1];
                s += (lane > 0) ? a : 0.f;
                s += (lane < 63) ? c : 0.f;
                R[mi] += s;
            }
        }
#pragma unroll
        for (int mi = 0; mi < 8; ++mi) {
            float score = R[mi] * inv;
            if (score > maxv[mi]) { maxv[mi] = score; maxi[mi] = l; }
        }
    }

#pragma unroll
    for (int mi = 0; mi < 8; ++mi) {
        float v = maxv[mi];
        int idx = maxi[mi];
#pragma unroll
        for (int off = 32; off >= 1; off >>= 1) {
            float v2 = __shfl_xor(v, off);
            int i2 = __shfl_xor(idx, off);
            if (v2 > v || (v2 == v && i2 < idx)) { v = v2; idx = i2; }
        }
        if (lane == 0) {
            int m = mh * 64 + mwbase + mi;
            atomicMax(&keys[m], pack_key(v, idx));
        }
    }
}

// ---------- K4: LDS-staged gather-fold. Block = (2 channels, batch). ----------
__global__ __launch_bounds__(256) void fold_kernel(const float* __restrict__ fc,
                                                   const float* __restrict__ fr,
                                                   const unsigned long long* __restrict__ keys,
                                                   float* __restrict__ out) {
    int b = blockIdx.y;
    int c0 = blockIdx.x * 2;
    __shared__ float frL[2 * 4096];
    __shared__ int idxL[4096];
    int t = threadIdx.x;

    const float* fsrc = fr + (size_t)b * CHW + (size_t)c0 * HW;
#pragma unroll
    for (int it = 0; it < 8; ++it) {
        int o = (it * 256 + t) * 4;
        *reinterpret_cast<float4*>(&frL[o]) = *reinterpret_cast<const float4*>(&fsrc[o]);
    }
#pragma unroll
    for (int it = 0; it < 16; ++it) {
        int m = it * 256 + t;
        unsigned long long kk = keys[(size_t)b * HW + m];
        idxL[m] = (int)(0xFFFFFFFFu - (unsigned)(kk & 0xFFFFFFFFull));
    }
    __syncthreads();

    int j = t & 63, w = t >> 6;
    int c = c0 + (w & 1);
    int i0 = (w >> 1) * 32;
    const float* frowL = &frL[(w & 1) * 4096];
    const float* fcrow = fc + (size_t)b * CHW + (size_t)c * HW;
    float* orow = out + (size_t)b * CHW + (size_t)c * HW;

    for (int i = i0; i < i0 + 32; ++i) {
        float acc = fcrow[i * 64 + j];
#pragma unroll
        for (int kh = 0; kh < 3; ++kh) {
            int mhp = i + 1 - kh;
            if ((unsigned)mhp >= 64u) continue;
#pragma unroll
            for (int kw = 0; kw < 3; ++kw) {
                int mwp = j + 1 - kw;
                float contrib = 0.f;
                if ((unsigned)mwp < 64u) {
                    int idx = idxL[mhp * 64 + mwp];
                    int sh = (idx >> 6) + kh - 1;
                    int sw = (idx & 63) + kw - 1;
                    if ((unsigned)sh < 64u && (unsigned)sw < 64u)
                        contrib = frowL[sh * 64 + sw];
                }
                acc += contrib;
            }
        }
        orow[i * 64 + j] = acc;
    }
}

// ---------- launch ----------
extern "C" void kernel_launch(void* const* d_in, const int* in_sizes, int n_in,
                              void* d_out, int out_size, void* d_ws, size_t ws_size,
                              hipStream_t stream) {
    const float* fc = (const float*)d_in[0];   // feature_current
    const float* fr = (const float*)d_in[1];   // feature_refer
    const float* frb = (const float*)d_in[2];  // feature_refer_blur
    float* out = (float*)d_out;

    char* ws = (char*)d_ws;
    unsigned long long* keys = (unsigned long long*)ws;  // 131072 B
    float* invn = (float*)(ws + 131072);                 //  65536 B
    float* sbuf = (float*)(ws + 196608);                 // 524288 B
    const size_t HDR = 720896;

    size_t abBytes = (size_t)2 * HW * 512 * sizeof(f16);  // 8,388,608 per batch
    size_t gBytes = (size_t)HW * HW * 4;                  // 67,108,864
    size_t needB = HDR + 4 * abBytes + gBytes;            // ~101.8 MB
    size_t needC = HDR + abBytes + gBytes;                // ~76.3 MB

    hipMemsetAsync(keys, 0, 131072, stream);
    sqsum_kernel<<<dim3(B_, 16, 8), 256, 0, stream>>>(frb, sbuf);
    invn_kernel<<<dim3(B_, 16), 256, 0, stream>>>(sbuf, invn);

    if (ws_size >= needC) {
        bool mergedConv = (ws_size >= needB);
        int nab = mergedConv ? 4 : 1;
        f16* AB = (f16*)(ws + HDR);
        float* G = (float*)(ws + HDR + (size_t)nab * abBytes);

        hipFuncSetAttribute(reinterpret_cast<const void*>(&gram256_kernel),
                            hipFuncAttributeMaxDynamicSharedMemorySize, 131072);

        if (mergedConv)
            conv_kernel<<<dim3(64, 4, 8), 256, 0, stream>>>(fc, frb, AB);

        for (int b = 0; b < B_; ++b) {
            if (!mergedConv)
                conv_kernel<<<dim3(64, 4, 2), 256, 0, stream>>>(
                    fc + (size_t)b * CHW, frb + (size_t)b * CHW, AB);
            f16* ABslot = AB + (size_t)(mergedConv ? b : 0) * 4194304;
            gram256_kernel<<<dim3(16, 16, 1), 512, 131072, stream>>>(ABslot, G);
            argmax3_kernel<<<dim3(64, 8, 1), 512, 0, stream>>>(
                G, invn + (size_t)b * HW, keys + (size_t)b * HW);
        }
    } else {
        float* G = (float*)(ws + HDR);
        int CW = 4096, PAD = 0;
        while (CW >= 256) {
            PAD = (CW == 4096) ? 0 : 128;
            size_t need = HDR + (size_t)HW * (CW + 2 * PAD) * 4;
            if (need <= ws_size) break;
            CW >>= 1;
        }
        int CWP = CW + 2 * PAD;
        for (int b = 0; b < B_; ++b) {
            for (int cb = 0; cb < HW; cb += CW) {
                int l_start = cb - PAD;
                gram_kernel<<<dim3(CWP / 128, 32), 256, 0, stream>>>(
                    fc + (size_t)b * CHW, frb + (size_t)b * CHW, G, l_start, CWP);
                argmax_kernel<<<dim3(64, CW / 256, 1), 512, 0, stream>>>(
                    G, invn + (size_t)b * HW, keys + (size_t)b * HW,
                    cb / 64, l_start, CWP);
            }
        }
    }
    fold_kernel<<<dim3(128, B_), 256, 0, stream>>>(fc, fr, keys, out);
}

// Round 16
// 304.129 us; speedup vs baseline: 1.0145x; 1.0145x over previous
//
#include <hip/hip_runtime.h>
#include <hip/hip_bf16.h>
#include <stdint.h>

#define HW 4096
#define C_ 256
#define B_ 4

static const size_t CHW = (size_t)C_ * HW;  // 1,048,576 elements per batch per tensor

typedef _Float16 f16;
typedef f16 f16x8 __attribute__((ext_vector_type(8)));
typedef float f32x4 __attribute__((ext_vector_type(4)));

#define AS1 __attribute__((address_space(1)))
#define AS3 __attribute__((address_space(3)))
#define GLL(src, dst) __builtin_amdgcn_global_load_lds((const AS1 uint32_t*)(src), (AS3 uint32_t*)(dst), 16, 0, 0)

// ---------- helpers ----------
__device__ __forceinline__ unsigned long long pack_key(float v, int i) {
    unsigned u = __float_as_uint(v);
    u = (u & 0x80000000u) ? ~u : (u | 0x80000000u);
    return ((unsigned long long)u << 32) | (unsigned long long)(0xFFFFFFFFu - (unsigned)i);
}

// ---------- K1a: per-pixel partial squared sums (8 channel-groups) ----------
__global__ __launch_bounds__(256) void sqsum_kernel(const float* __restrict__ frb,
                                                    float* __restrict__ sbuf) {
    int b = blockIdx.x;
    int ij = blockIdx.y * 256 + threadIdx.x;
    int g = blockIdx.z;
    const float* p = frb + (size_t)b * CHW + (size_t)g * 32 * HW + ij;
    float s = 0.f;
#pragma unroll 8
    for (int c = 0; c < 32; ++c) {
        float v = p[(size_t)c * HW];
        s = fmaf(v, v, s);
    }
    sbuf[((size_t)b * 8 + g) * HW + ij] = s;
}

// ---------- K1b: sum partials -> 3x3 box sum -> 1/max(sqrt, eps) ----------
__global__ __launch_bounds__(256) void invn_kernel(const float* __restrict__ sbuf,
                                                   float* __restrict__ invn) {
    int b = blockIdx.x;
    int l = blockIdx.y * 256 + threadIdx.x;
    int lh = l >> 6, lw = l & 63;
    float s = 0.f;
#pragma unroll
    for (int dh = -1; dh <= 1; ++dh) {
        int h = lh + dh;
        if ((unsigned)h >= 64u) continue;
#pragma unroll
        for (int dw = -1; dw <= 1; ++dw) {
            int w = lw + dw;
            if ((unsigned)w >= 64u) continue;
            float t = 0.f;
#pragma unroll
            for (int g = 0; g < 8; ++g)
                t += sbuf[((size_t)b * 8 + g) * HW + h * 64 + w];
            s += t;
        }
    }
    float n = sqrtf(s);
    invn[b * HW + l] = 1.0f / fmaxf(n, 1e-12f);
}

// ---------- conv: fp32 [256][4096] -> f16 hi/lo, m-major [4096][512] ----------
__global__ __launch_bounds__(256) void conv_kernel(const float* __restrict__ fcB,
                                                   const float* __restrict__ frbB,
                                                   f16* __restrict__ AB) {
    int zz = blockIdx.z;
    int b = zz >> 1;
    const float* src = ((zz & 1) ? frbB : fcB) + (size_t)b * CHW;
    f16* dst = AB + (size_t)b * 4194304 + (size_t)(zz & 1) * 2097152;
    __shared__ float T[64][65];
    int m0 = blockIdx.x * 64, k0 = blockIdx.y * 64;
    int t = threadIdx.x;
    int kl = t >> 4, mq = (t & 15) * 4;
#pragma unroll
    for (int it = 0; it < 4; ++it) {
        float4 v = *reinterpret_cast<const float4*>(src + (size_t)(k0 + kl + it * 16) * HW + m0 + mq);
        T[kl + it * 16][mq + 0] = v.x;
        T[kl + it * 16][mq + 1] = v.y;
        T[kl + it * 16][mq + 2] = v.z;
        T[kl + it * 16][mq + 3] = v.w;
    }
    __syncthreads();
    int ml = t >> 2, kc = (t & 3) * 16;
    f16x8 h0, h1, lo0, lo1;
#pragma unroll
    for (int j = 0; j < 8; ++j) {
        float a = T[kc + j][ml];
        f16 h = (f16)a;
        h0[j] = h;
        lo0[j] = (f16)(a - (float)h);
        float a2 = T[kc + 8 + j][ml];
        f16 h2 = (f16)a2;
        h1[j] = h2;
        lo1[j] = (f16)(a2 - (float)h2);
    }
    size_t base = (size_t)(m0 + ml) * 512 + k0 + kc;
    *reinterpret_cast<f16x8*>(dst + base) = h0;
    *reinterpret_cast<f16x8*>(dst + base + 8) = h1;
    *reinterpret_cast<f16x8*>(dst + base + 256) = lo0;
    *reinterpret_cast<f16x8*>(dst + base + 264) = lo1;
}

// ---------- K2 (MFMA, 256^2 8-phase): G = 3-product fp16-split Gram, K=768 ----------
// r15 ERRATA: swz=(row&3) left a 4-way bank conflict (64-B rows: bank period = 2
// rows; rows 0,4,8,12 in one fragment group collided -> 2.36M conflicts). Fixed
// swz=(row>>1)&3: the 8 (parity, slot) classes cover all 32 banks, 2 rows/class
// -> 2-way (free, m136). Same involution on staging source and ds_read; G is
// bit-identical to the 128^2 kernel (same t-asc/kk-asc accumulation order).
__global__ __launch_bounds__(512, 2) void gram256_kernel(const f16* __restrict__ ABbase,
                                                         float* __restrict__ Gbase) {
    extern __shared__ char lds[];
    char* ldsA = lds;            // 65536 B
    char* ldsB = lds + 65536;    // 65536 B
    const f16* Af = ABbase;
    const f16* Bf = Af + 2097152;
    float* G = Gbase;

    int tid = threadIdx.x;
    int lane = tid & 63;
    int wave = tid >> 6;
    int wr = wave >> 2, wc = wave & 3;

    // XCD-affinity remap of the 16x16 grid (bijective; dispatch id x-fastest)
    int id = blockIdx.y * 16 + blockIdx.x;
    int xcd = id & 7, local = id >> 3;       // local 0..31
    int bx = (xcd & 1) * 8 + (local & 7);    // 0..15
    int by = (xcd >> 1) * 4 + (local >> 3);  // 0..15
    int m0 = by * 256, l0 = bx * 256;

    f32x4 acc[8][4] = {};

    // staging sources: thread handles rows r0 (i=0) and r0+128 (i=1), chunk s0.
    // source swizzle slot = s0 ^ ((r0>>1)&3)  (same for r0+128: bit7 unused)
    int r0 = tid >> 2, s0 = tid & 3;
    const char* sA0 = (const char*)Af + (size_t)(m0 + r0) * 1024 + ((s0 ^ ((r0 >> 1) & 3)) << 4);
    const char* sB0 = (const char*)Bf + (size_t)(l0 + r0) * 1024 + ((s0 ^ ((r0 >> 1) & 3)) << 4);
    unsigned wbase = (unsigned)(tid & ~63) * 16;  // wave-uniform LDS dest base

#define STAGE_A(su, h, kb)                                                       \
    do {                                                                         \
        GLL(sA0 + (kb) + (h) * 64, ldsA + (su) * 32768 + (h) * 16384 + wbase);   \
        GLL(sA0 + 131072 + (kb) + (h) * 64,                                      \
            ldsA + (su) * 32768 + (h) * 16384 + wbase + 8192);                   \
    } while (0)
#define STAGE_B(su, h, kb)                                                       \
    do {                                                                         \
        GLL(sB0 + (kb) + (h) * 64, ldsB + (su) * 32768 + (h) * 16384 + wbase);   \
        GLL(sB0 + 131072 + (kb) + (h) * 64,                                      \
            ldsB + (su) * 32768 + (h) * 16384 + wbase + 8192);                   \
    } while (0)

    // LDS read bases: slot = kc ^ ((row>>1)&3); row bits 1-2 == lane bits 1-2
    unsigned rsw = (unsigned)(((lane >> 4) ^ ((lane >> 1) & 3)) << 4);
    unsigned aRow = (unsigned)((wr * 128 + (lane & 15)) * 64) + rsw;
    unsigned bRow = (unsigned)((wc * 64 + (lane & 15)) * 64) + rsw;

    const int akbArr[12] = {0, 128, 256, 384, 512, 640, 768, 896, 0, 128, 256, 384};
    const int bkbArr[12] = {0, 128, 256, 384, 0, 128, 256, 384, 512, 640, 768, 896};

    // prologue: stage tile 0 fully, drain, publish
    STAGE_A(0, 0, akbArr[0]);
    STAGE_B(0, 0, bkbArr[0]);
    STAGE_A(0, 1, akbArr[0]);
    STAGE_B(0, 1, bkbArr[0]);
    asm volatile("s_waitcnt vmcnt(0)" ::: "memory");
    __builtin_amdgcn_s_barrier();

    f16x8 av[4], bv[4];
#pragma unroll
    for (int t = 0; t < 12; ++t) {
        const int slot = t & 1, su = slot ^ 1;
        const bool pf = (t < 11);
        const int akbN = pf ? akbArr[t + 1] : 0;
        const int bkbN = pf ? bkbArr[t + 1] : 0;
        const char* Ab0 = ldsA + slot * 32768;            // kk0 half
        const char* Bb0 = ldsB + slot * 32768;
        const char* Ab1 = Ab0 + 16384;                    // kk1 half
        const char* Bb1 = Bb0 + 16384;

        // ---- phase 1: (kk0, m-lo) ----
#pragma unroll
        for (int ni = 0; ni < 4; ++ni)
            bv[ni] = *reinterpret_cast<const f16x8*>(Bb0 + bRow + ni * 1024);
#pragma unroll
        for (int q = 0; q < 4; ++q)
            av[q] = *reinterpret_cast<const f16x8*>(Ab0 + aRow + q * 1024);
        if (pf) STAGE_A(su, 0, akbN);
        __builtin_amdgcn_s_barrier();
        __builtin_amdgcn_s_setprio(1);
#pragma unroll
        for (int q = 0; q < 4; ++q)
#pragma unroll
            for (int ni = 0; ni < 4; ++ni)
                acc[q][ni] = __builtin_amdgcn_mfma_f32_16x16x32_f16(av[q], bv[ni], acc[q][ni], 0, 0, 0);
        __builtin_amdgcn_s_setprio(0);
        __builtin_amdgcn_s_barrier();

        // ---- phase 2: (kk0, m-hi) ----
#pragma unroll
        for (int q = 0; q < 4; ++q)
            av[q] = *reinterpret_cast<const f16x8*>(Ab0 + aRow + 4096 + q * 1024);
        if (pf) STAGE_B(su, 0, bkbN);
        __builtin_amdgcn_s_barrier();
        __builtin_amdgcn_s_setprio(1);
#pragma unroll
        for (int q = 0; q < 4; ++q)
#pragma unroll
            for (int ni = 0; ni < 4; ++ni)
                acc[4 + q][ni] = __builtin_amdgcn_mfma_f32_16x16x32_f16(av[q], bv[ni], acc[4 + q][ni], 0, 0, 0);
        __builtin_amdgcn_s_setprio(0);
        if (t < 11) asm volatile("s_waitcnt vmcnt(4)" ::: "memory");
        else        asm volatile("s_waitcnt vmcnt(0)" ::: "memory");
        __builtin_amdgcn_s_barrier();

        // ---- phase 3: (kk1, m-lo) ----
#pragma unroll
        for (int ni = 0; ni < 4; ++ni)
            bv[ni] = *reinterpret_cast<const f16x8*>(Bb1 + bRow + ni * 1024);
#pragma unroll
        for (int q = 0; q < 4; ++q)
            av[q] = *reinterpret_cast<const f16x8*>(Ab1 + aRow + q * 1024);
        if (pf) STAGE_A(su, 1, akbN);
        __builtin_amdgcn_s_barrier();
        __builtin_amdgcn_s_setprio(1);
#pragma unroll
        for (int q = 0; q < 4; ++q)
#pragma unroll
            for (int ni = 0; ni < 4; ++ni)
                acc[q][ni] = __builtin_amdgcn_mfma_f32_16x16x32_f16(av[q], bv[ni], acc[q][ni], 0, 0, 0);
        __builtin_amdgcn_s_setprio(0);
        __builtin_amdgcn_s_barrier();

        // ---- phase 4: (kk1, m-hi) ----
#pragma unroll
        for (int q = 0; q < 4; ++q)
            av[q] = *reinterpret_cast<const f16x8*>(Ab1 + aRow + 4096 + q * 1024);
        if (pf) STAGE_B(su, 1, bkbN);
        __builtin_amdgcn_s_barrier();
        __builtin_amdgcn_s_setprio(1);
#pragma unroll
        for (int q = 0; q < 4; ++q)
#pragma unroll
            for (int ni = 0; ni < 4; ++ni)
                acc[4 + q][ni] = __builtin_amdgcn_mfma_f32_16x16x32_f16(av[q], bv[ni], acc[4 + q][ni], 0, 0, 0);
        __builtin_amdgcn_s_setprio(0);
        if (t < 11) asm volatile("s_waitcnt vmcnt(4)" ::: "memory");
        __builtin_amdgcn_s_barrier();
    }
#undef STAGE_A
#undef STAGE_B

    // epilogue: C/D layout col=lane&15, row=(lane>>4)*4+r
#pragma unroll
    for (int mi = 0; mi < 8; ++mi) {
#pragma unroll
        for (int ni = 0; ni < 4; ++ni) {
            int n = l0 + wc * 64 + ni * 16 + (lane & 15);
            int mr = m0 + wr * 128 + mi * 16 + (lane >> 4) * 4;
#pragma unroll
            for (int r = 0; r < 4; ++r)
                G[(size_t)(mr + r) * HW + n] = acc[mi][ni][r];
        }
    }
}

// ---------- K2 fallback: fp32 Gram GEMM (chunked) ----------
#define TBK 32
__global__ __launch_bounds__(256) void gram_kernel(const float* __restrict__ Amat,
                                                   const float* __restrict__ Bmat,
                                                   float* __restrict__ G,
                                                   int l_start, int CWP) {
    __shared__ float As[TBK][128];
    __shared__ float Bs[TBK][128];
    int m0 = blockIdx.y * 128;
    int l0g = l_start + blockIdx.x * 128;
    bool inrange = (l0g >= 0 && l0g < HW);
    int tid = threadIdx.x;
    int tx = tid & 15;
    int ty = tid >> 4;
    float acc[8][8] = {};

    if (inrange) {
        for (int k0 = 0; k0 < C_; k0 += TBK) {
#pragma unroll
            for (int it = 0; it < 4; ++it) {
                int idx = tid + it * 256;
                int r = idx >> 5;
                int c4 = idx & 31;
                float4 av = *reinterpret_cast<const float4*>(Amat + (size_t)(k0 + r) * HW + m0 + c4 * 4);
                *reinterpret_cast<float4*>(&As[r][c4 * 4]) = av;
                float4 bv = *reinterpret_cast<const float4*>(Bmat + (size_t)(k0 + r) * HW + l0g + c4 * 4);
                *reinterpret_cast<float4*>(&Bs[r][c4 * 4]) = bv;
            }
            __syncthreads();
#pragma unroll
            for (int k = 0; k < TBK; ++k) {
                float a[8], bb[8];
                *(float4*)&a[0] = *(float4*)&As[k][ty * 8];
                *(float4*)&a[4] = *(float4*)&As[k][ty * 8 + 4];
                *(float4*)&bb[0] = *(float4*)&Bs[k][tx * 8];
                *(float4*)&bb[4] = *(float4*)&Bs[k][tx * 8 + 4];
#pragma unroll
                for (int i = 0; i < 8; ++i)
#pragma unroll
                    for (int j = 0; j < 8; ++j)
                        acc[i][j] = fmaf(a[i], bb[j], acc[i][j]);
            }
            __syncthreads();
        }
    }
#pragma unroll
    for (int i = 0; i < 8; ++i) {
        int m = m0 + ty * 8 + i;
        float* row = G + (size_t)m * CWP + blockIdx.x * 128 + tx * 8;
        *(float4*)row = *(float4*)&acc[i][0];
        *(float4*)(row + 4) = *(float4*)&acc[i][4];
    }
}

// ---------- K3 (v3): diagonal-separable 9-shift sum + argmax ----------
__global__ __launch_bounds__(512, 4) void argmax3_kernel(const float* __restrict__ Gbase,
                                                         const float* __restrict__ invnB,
                                                         unsigned long long* __restrict__ keysB) {
    const float* G = Gbase + (size_t)blockIdx.z * ((size_t)HW * HW);
    const float* invn = invnB + (size_t)blockIdx.z * HW;
    unsigned long long* keys = keysB + (size_t)blockIdx.z * HW;

    int id = blockIdx.y * gridDim.x + blockIdx.x;  // 0..511
    int xcd = id & 7, pos = id >> 3;               // pos 0..63
    int mh = xcd * 8 + (pos >> 3);
    int c0 = (pos & 7) * 8;

    int lane = threadIdx.x & 63;
    int wave = threadIdx.x >> 6;
    int mwb = wave * 8;

    bool laneUp = lane >= 1, laneDn = lane <= 62;
    bool mhUp = mh >= 1, mhDn = mh <= 62;

    unsigned rowOff[3][10];
    int br0 = max(mh - 1, 0) * 64, br1 = mh * 64, br2 = min(mh + 1, 63) * 64;
#pragma unroll
    for (int j = 0; j < 10; ++j) {
        int mwr = min(max(mwb - 1 + j, 0), 63);
        rowOff[0][j] = (unsigned)((br0 + mwr) * 4096 + lane);
        rowOff[1][j] = (unsigned)((br1 + mwr) * 4096 + lane);
        rowOff[2][j] = (unsigned)((br2 + mwr) * 4096 + lane);
    }

    float A[8], B[8];
#pragma unroll
    for (int i = 0; i < 8; ++i) { A[i] = 0.f; B[i] = 0.f; }
    float maxv[8];
    int maxi[8];
#pragma unroll
    for (int i = 0; i < 8; ++i) { maxv[i] = -INFINITY; maxi[i] = 0; }
    float invPrev = 0.f;

    for (int c = c0 - 1; c <= c0 + 8; ++c) {
        int cc = min(max(c, 0), 63);
        unsigned colOff = (unsigned)(cc * 64);
        float g[3][10];
#pragma unroll
        for (int b = 0; b < 3; ++b)
#pragma unroll
            for (int j = 0; j < 10; ++j)
                g[b][j] = G[(size_t)(rowOff[b][j] + colOff)];
        float invCur = invn[colOff + lane];

        if (c - 1 >= c0) {
            bool vp = mhDn && (c <= 63);
            int lbase = (c - 1) * 64 + lane;
#pragma unroll
            for (int i = 0; i < 8; ++i) {
                float up = __shfl_up(g[2][i], 1);
                float dn = __shfl_down(g[2][i + 2], 1);
                float w = g[2][i + 1];
                w += (laneUp && (mwb + i >= 1)) ? up : 0.f;
                w += (laneDn && (mwb + i <= 62)) ? dn : 0.f;
                float R = A[i] + (vp ? w : 0.f);
                float score = R * invPrev;
                if (score > maxv[i]) { maxv[i] = score; maxi[i] = lbase; }
            }
        }
        bool vm = mhUp && (c >= 0);
#pragma unroll
        for (int i = 0; i < 8; ++i) {
            float up1 = __shfl_up(g[1][i], 1);
            float dn1 = __shfl_down(g[1][i + 2], 1);
            float w1 = g[1][i + 1];
            w1 += (laneUp && (mwb + i >= 1)) ? up1 : 0.f;
            w1 += (laneDn && (mwb + i <= 62)) ? dn1 : 0.f;
            A[i] = B[i] + w1;

            float up0 = __shfl_up(g[0][i], 1);
            float dn0 = __shfl_down(g[0][i + 2], 1);
            float w0 = g[0][i + 1];
            w0 += (laneUp && (mwb + i >= 1)) ? up0 : 0.f;
            w0 += (laneDn && (mwb + i <= 62)) ? dn0 : 0.f;
            B[i] = vm ? w0 : 0.f;
        }
        invPrev = invCur;
    }

#pragma unroll
    for (int i = 0; i < 8; ++i) {
        float v = maxv[i];
        int idx = maxi[i];
#pragma unroll
        for (int off = 32; off >= 1; off >>= 1) {
            float v2 = __shfl_xor(v, off);
            int i2 = __shfl_xor(idx, off);
            if (v2 > v || (v2 == v && i2 < idx)) { v = v2; idx = i2; }
        }
        if (lane == 0) atomicMax(&keys[mh * 64 + mwb + i], pack_key(v, idx));
    }
}

// ---------- K3 fallback (chunked-G path): tap kernel ----------
__global__ __launch_bounds__(512, 8) void argmax_kernel(const float* __restrict__ Gbase,
                                                        const float* __restrict__ invnB,
                                                        unsigned long long* __restrict__ keysB,
                                                        int lh0, int l_start, int CWP) {
    const float* G = Gbase;
    const float* invn = invnB;
    unsigned long long* keys = keysB;
    int mh = blockIdx.x;
    int lh_base = lh0 + blockIdx.y * 4;
    int wave = threadIdx.x >> 6;
    int lane = threadIdx.x & 63;
    int mwbase = wave * 8;

    float maxv[8];
    int maxi[8];
#pragma unroll
    for (int i = 0; i < 8; ++i) { maxv[i] = -INFINITY; maxi[i] = 0; }

    for (int lhs = 0; lhs < 4; ++lhs) {
        int lh = lh_base + lhs;
        int l = lh * 64 + lane;
        float inv = invn[l];
        float R[8];
#pragma unroll
        for (int i = 0; i < 8; ++i) R[i] = 0.f;

#pragma unroll
        for (int dh = -1; dh <= 1; ++dh) {
            if ((unsigned)(mh + dh) >= 64u || (unsigned)(lh + dh) >= 64u) continue;
            const float* Gb = G + (size_t)((mh + dh) * 64) * CWP + ((lh + dh) * 64 - l_start) + lane;
            float v[10];
#pragma unroll
            for (int j = 0; j < 10; ++j) {
                int mw2 = mwbase - 1 + j;
                int mwc = min(max(mw2, 0), 63);
                float tv = Gb[(size_t)mwc * CWP];
                v[j] = ((unsigned)mw2 < 64u) ? tv : 0.f;
            }
#pragma unroll
            for (int mi = 0; mi < 8; ++mi) {
                float a = __shfl_up(v[mi], 1);
                float c = __shfl_down(v[mi + 2], 1);
                float s = v[mi + 1];
                s += (lane > 0) ? a : 0.f;
                s += (lane < 63) ? c : 0.f;
                R[mi] += s;
            }
        }
#pragma unroll
        for (int mi = 0; mi < 8; ++mi) {
            float score = R[mi] * inv;
            if (score > maxv[mi]) { maxv[mi] = score; maxi[mi] = l; }
        }
    }

#pragma unroll
    for (int mi = 0; mi < 8; ++mi) {
        float v = maxv[mi];
        int idx = maxi[mi];
#pragma unroll
        for (int off = 32; off >= 1; off >>= 1) {
            float v2 = __shfl_xor(v, off);
            int i2 = __shfl_xor(idx, off);
            if (v2 > v || (v2 == v && i2 < idx)) { v = v2; idx = i2; }
        }
        if (lane == 0) {
            int m = mh * 64 + mwbase + mi;
            atomicMax(&keys[m], pack_key(v, idx));
        }
    }
}

// ---------- K4: LDS-staged gather-fold. Block = (2 channels, batch). ----------
__global__ __launch_bounds__(256) void fold_kernel(const float* __restrict__ fc,
                                                   const float* __restrict__ fr,
                                                   const unsigned long long* __restrict__ keys,
                                                   float* __restrict__ out) {
    int b = blockIdx.y;
    int c0 = blockIdx.x * 2;
    __shared__ float frL[2 * 4096];
    __shared__ int idxL[4096];
    int t = threadIdx.x;

    const float* fsrc = fr + (size_t)b * CHW + (size_t)c0 * HW;
#pragma unroll
    for (int it = 0; it < 8; ++it) {
        int o = (it * 256 + t) * 4;
        *reinterpret_cast<float4*>(&frL[o]) = *reinterpret_cast<const float4*>(&fsrc[o]);
    }
#pragma unroll
    for (int it = 0; it < 16; ++it) {
        int m = it * 256 + t;
        unsigned long long kk = keys[(size_t)b * HW + m];
        idxL[m] = (int)(0xFFFFFFFFu - (unsigned)(kk & 0xFFFFFFFFull));
    }
    __syncthreads();

    int j = t & 63, w = t >> 6;
    int c = c0 + (w & 1);
    int i0 = (w >> 1) * 32;
    const float* frowL = &frL[(w & 1) * 4096];
    const float* fcrow = fc + (size_t)b * CHW + (size_t)c * HW;
    float* orow = out + (size_t)b * CHW + (size_t)c * HW;

    for (int i = i0; i < i0 + 32; ++i) {
        float acc = fcrow[i * 64 + j];
#pragma unroll
        for (int kh = 0; kh < 3; ++kh) {
            int mhp = i + 1 - kh;
            if ((unsigned)mhp >= 64u) continue;
#pragma unroll
            for (int kw = 0; kw < 3; ++kw) {
                int mwp = j + 1 - kw;
                float contrib = 0.f;
                if ((unsigned)mwp < 64u) {
                    int idx = idxL[mhp * 64 + mwp];
                    int sh = (idx >> 6) + kh - 1;
                    int sw = (idx & 63) + kw - 1;
                    if ((unsigned)sh < 64u && (unsigned)sw < 64u)
                        contrib = frowL[sh * 64 + sw];
                }
                acc += contrib;
            }
        }
        orow[i * 64 + j] = acc;
    }
}

// ---------- launch ----------
extern "C" void kernel_launch(void* const* d_in, const int* in_sizes, int n_in,
                              void* d_out, int out_size, void* d_ws, size_t ws_size,
                              hipStream_t stream) {
    const float* fc = (const float*)d_in[0];   // feature_current
    const float* fr = (const float*)d_in[1];   // feature_refer
    const float* frb = (const float*)d_in[2];  // feature_refer_blur
    float* out = (float*)d_out;

    char* ws = (char*)d_ws;
    unsigned long long* keys = (unsigned long long*)ws;  // 131072 B
    float* invn = (float*)(ws + 131072);                 //  65536 B
    float* sbuf = (float*)(ws + 196608);                 // 524288 B
    const size_t HDR = 720896;

    size_t abBytes = (size_t)2 * HW * 512 * sizeof(f16);  // 8,388,608 per batch
    size_t gBytes = (size_t)HW * HW * 4;                  // 67,108,864
    size_t needB = HDR + 4 * abBytes + gBytes;            // ~101.8 MB
    size_t needC = HDR + abBytes + gBytes;                // ~76.3 MB

    hipMemsetAsync(keys, 0, 131072, stream);
    sqsum_kernel<<<dim3(B_, 16, 8), 256, 0, stream>>>(frb, sbuf);
    invn_kernel<<<dim3(B_, 16), 256, 0, stream>>>(sbuf, invn);

    if (ws_size >= needC) {
        bool mergedConv = (ws_size >= needB);
        int nab = mergedConv ? 4 : 1;
        f16* AB = (f16*)(ws + HDR);
        float* G = (float*)(ws + HDR + (size_t)nab * abBytes);

        hipFuncSetAttribute(reinterpret_cast<const void*>(&gram256_kernel),
                            hipFuncAttributeMaxDynamicSharedMemorySize, 131072);

        if (mergedConv)
            conv_kernel<<<dim3(64, 4, 8), 256, 0, stream>>>(fc, frb, AB);

        for (int b = 0; b < B_; ++b) {
            if (!mergedConv)
                conv_kernel<<<dim3(64, 4, 2), 256, 0, stream>>>(
                    fc + (size_t)b * CHW, frb + (size_t)b * CHW, AB);
            f16* ABslot = AB + (size_t)(mergedConv ? b : 0) * 4194304;
            gram256_kernel<<<dim3(16, 16, 1), 512, 131072, stream>>>(ABslot, G);
            argmax3_kernel<<<dim3(64, 8, 1), 512, 0, stream>>>(
                G, invn + (size_t)b * HW, keys + (size_t)b * HW);
        }
    } else {
        float* G = (float*)(ws + HDR);
        int CW = 4096, PAD = 0;
        while (CW >= 256) {
            PAD = (CW == 4096) ? 0 : 128;
            size_t need = HDR + (size_t)HW * (CW + 2 * PAD) * 4;
            if (need <= ws_size) break;
            CW >>= 1;
        }
        int CWP = CW + 2 * PAD;
        for (int b = 0; b < B_; ++b) {
            for (int cb = 0; cb < HW; cb += CW) {
                int l_start = cb - PAD;
                gram_kernel<<<dim3(CWP / 128, 32), 256, 0, stream>>>(
                    fc + (size_t)b * CHW, frb + (size_t)b * CHW, G, l_start, CWP);
                argmax_kernel<<<dim3(64, CW / 256, 1), 512, 0, stream>>>(
                    G, invn + (size_t)b * HW, keys + (size_t)b * HW,
                    cb / 64, l_start, CWP);
            }
        }
    }
    fold_kernel<<<dim3(128, B_), 256, 0, stream>>>(fc, fr, keys, out);
}